// Round 7
// baseline (778.794 us; speedup 1.0000x reference)
//
#include <hip/hip_runtime.h>
#include <math.h>

// RoutingLayer: N=50000 rows, M=32 neighbors, D=128 = K=8 capsules x 16 dims,
// 6 routing iterations. One wave per row; lane = k*8 + j owns ALL 16 dims of
// capsule k for the 4 neighbors m = j, j+8, j+16, j+24.
//
// r7 == r6 minus the H8Cast union (it blocked SROA -> z/xch spilled to scratch:
// FETCH 1.9GB / WRITE 1.2GB, 721us). Loads are uint4 + per-dword bit_cast to h2.
//  - prologue normalizes x into an fp16 table xn[(N+1) x 128] (zero pad row N)
//  - z packed h2[4][8] = 32 VGPRs; dots v_dot2_f32_f16; updates v_fma_mix
//  - butterfly / softmax / norm stay fp32
//  - __launch_bounds__(256,5)

constexpr int NROWS = 50000;
constexpr int MN = 32;
constexpr int DDIM = 128;
constexpr float FEPS2 = 1e-24f;  // eps^2, eps = 1e-12 (torch F.normalize)
constexpr float LOG2E = 1.44269504088896340736f;

typedef _Float16 h2 __attribute__((ext_vector_type(2)));
typedef __fp16 fp16x2 __attribute__((ext_vector_type(2)));  // builtin ABI type

#if __has_builtin(__builtin_amdgcn_rcpf)
__device__ __forceinline__ float fast_rcp(float v) { return __builtin_amdgcn_rcpf(v); }
#else
__device__ __forceinline__ float fast_rcp(float v) { return __frcp_rn(v); }
#endif
#if __has_builtin(__builtin_amdgcn_rsqf)
__device__ __forceinline__ float fast_rsq(float v) { return __builtin_amdgcn_rsqf(v); }
#else
__device__ __forceinline__ float fast_rsq(float v) { return rsqrtf(v); }
#endif
#if __has_builtin(__builtin_amdgcn_exp2f)
__device__ __forceinline__ float fast_exp2(float v) { return __builtin_amdgcn_exp2f(v); }
#else
__device__ __forceinline__ float fast_exp2(float v) { return exp2f(v); }
#endif

// v + dpp_perm(v): quad_perm(1,0,3,2)=xor1 -> 0xB1; quad_perm(2,3,0,1)=xor2 -> 0x4E;
// row_ror:8 (xor8 within row of 16) -> 0x128. Fuses to a single v_add with DPP.
template <int CTRL>
__device__ __forceinline__ float dpp_add(float v) {
    int r = __builtin_amdgcn_update_dpp(0, __builtin_bit_cast(int, v), CTRL, 0xF, 0xF, true);
    return v + __builtin_bit_cast(float, r);
}

// fp32 accum dot of two f16 pairs: v_dot2_f32_f16.
__device__ __forceinline__ float hdot2(h2 a, h2 b, float c) {
#if __has_builtin(__builtin_amdgcn_fdot2)
    return __builtin_amdgcn_fdot2(__builtin_bit_cast(fp16x2, a),
                                  __builtin_bit_cast(fp16x2, b), c, false);
#else
    return fmaf((float)a[0], (float)b[0], fmaf((float)a[1], (float)b[1], c));
#endif
}

__device__ __forceinline__ h2 pack2(float a, float b) {
#if __has_builtin(__builtin_amdgcn_cvt_pkrtz)
    return __builtin_bit_cast(h2, __builtin_amdgcn_cvt_pkrtz(a, b));
#else
    h2 r; r[0] = (_Float16)a; r[1] = (_Float16)b; return r;
#endif
}

// fp16 src x fp32 scalar + fp32 acc -> v_fma_mix_f32 (pattern-matched by LLVM).
__device__ __forceinline__ float mixfma(_Float16 h, float s, float acc) {
    return fmaf((float)h, s, acc);
}

// Load 16 halves (32B) as two uint4 and scatter into 8 h2 regs (no union: SROA-safe).
__device__ __forceinline__ void load8h2(h2 (&dst)[8], const _Float16* __restrict__ p) {
    const uint4* q = reinterpret_cast<const uint4*>(p);
    uint4 a = q[0], b = q[1];
    dst[0] = __builtin_bit_cast(h2, a.x);
    dst[1] = __builtin_bit_cast(h2, a.y);
    dst[2] = __builtin_bit_cast(h2, a.z);
    dst[3] = __builtin_bit_cast(h2, a.w);
    dst[4] = __builtin_bit_cast(h2, b.x);
    dst[5] = __builtin_bit_cast(h2, b.y);
    dst[6] = __builtin_bit_cast(h2, b.z);
    dst[7] = __builtin_bit_cast(h2, b.w);
}

__device__ __forceinline__ void load16(float (&dst)[16], const float* __restrict__ p) {
    const float4* q = reinterpret_cast<const float4*>(p);
#pragma unroll
    for (int i = 0; i < 4; ++i) {
        float4 v = q[i];
        dst[4 * i + 0] = v.x; dst[4 * i + 1] = v.y;
        dst[4 * i + 2] = v.z; dst[4 * i + 3] = v.w;
    }
}

__device__ __forceinline__ void normalize16(float (&v)[16]) {
    float a = v[0] * v[0], b = v[1] * v[1];
#pragma unroll
    for (int d = 2; d < 16; d += 2) {
        a = fmaf(v[d], v[d], a);
        b = fmaf(v[d + 1], v[d + 1], b);
    }
    float iv = fast_rsq(fmaxf(a + b, FEPS2));
#pragma unroll
    for (int d = 0; d < 16; ++d) v[d] *= iv;
}

// sum over the 8 j-lanes (lane bits 0..2), broadcast to all 8.
__device__ __forceinline__ void butterfly8(float (&u)[16]) {
#pragma unroll
    for (int d = 0; d < 16; ++d) u[d] = dpp_add<0xB1>(u[d]);
#pragma unroll
    for (int d = 0; d < 16; ++d) u[d] = dpp_add<0x4E>(u[d]);
#pragma unroll
    for (int d = 0; d < 16; ++d) u[d] += __shfl_xor(u[d], 4);
}

// rsqrt(max(||u||^2, eps^2)) * log2(e) -- combined dot-scale constant.
__device__ __forceinline__ float inv_norm_log2e(const float (&u)[16]) {
    float a = u[0] * u[0], b = u[1] * u[1];
#pragma unroll
    for (int d = 2; d < 16; d += 2) {
        a = fmaf(u[d], u[d], a);
        b = fmaf(u[d + 1], u[d + 1], b);
    }
    return fast_rsq(fmaxf(a + b, FEPS2)) * LOG2E;
}

// Prologue: per-capsule L2-normalize x into fp16 xn[(N+1) x 128]; row N = zeros.
// One float4 (input) per thread -> 4 halves (8B) out; lane-quad = one capsule.
__global__ __launch_bounds__(256) void norm_kernel(const float* __restrict__ x,
                                                   _Float16* __restrict__ xn) {
    int t = blockIdx.x * 256 + threadIdx.x;
    constexpr int TOTAL = (NROWS + 1) * (DDIM / 4);  // 50001*32
    if (t >= TOTAL) return;
    int n = t >> 5;
    float4 v = make_float4(0.f, 0.f, 0.f, 0.f);
    if (n < NROWS) v = reinterpret_cast<const float4*>(x)[t];
    float ss = v.x * v.x;
    ss = fmaf(v.y, v.y, ss);
    ss = fmaf(v.z, v.z, ss);
    ss = fmaf(v.w, v.w, ss);
    ss = dpp_add<0xB1>(ss);  // quad (4 threads) = one capsule (16 floats)
    ss = dpp_add<0x4E>(ss);
    float iv = fast_rsq(fmaxf(ss, FEPS2));
    h2 lo = pack2(v.x * iv, v.y * iv);
    h2 hi = pack2(v.z * iv, v.w * iv);
    float2 w;
    w.x = __builtin_bit_cast(float, lo);
    w.y = __builtin_bit_cast(float, hi);
    reinterpret_cast<float2*>(xn)[t] = w;  // 8B per thread
}

template <bool PRENORM>
__global__ __launch_bounds__(256, 5) void routing_kernel(const void* __restrict__ xsrc,
                                                         const int* __restrict__ nbr,
                                                         float* __restrict__ out) {
    const int lane = threadIdx.x & 63;
    const int n = blockIdx.x * 4 + (threadIdx.x >> 6);  // 12500*4 = 50000
    const int j = lane & 7;
    const int k = lane >> 3;

    const int* __restrict__ nrow = nbr + n * MN;
    int idx[4];
#pragma unroll
    for (int t = 0; t < 4; ++t) idx[t] = nrow[j + 8 * t];

    h2 z[4][8];   // 4 neighbors x 16 dims, packed f16 pairs (32 VGPRs)
    h2 xch[8];    // own capsule, packed f16 (later scaled by 1/8)

    if constexpr (PRENORM) {
        const _Float16* xh = (const _Float16*)xsrc;
        load8h2(xch, xh + (size_t)n * DDIM + k * 16);
#pragma unroll
        for (int t = 0; t < 4; ++t) {
            // idx == NROWS hits the zero pad row: no bounds check, no normalize
            load8h2(z[t], xh + (size_t)idx[t] * DDIM + k * 16);
        }
    } else {
        const float* xf = (const float*)xsrc;
        float tmp[16];
        load16(tmp, xf + (size_t)n * DDIM + k * 16);
        normalize16(tmp);
#pragma unroll
        for (int q = 0; q < 8; ++q) xch[q] = pack2(tmp[2 * q], tmp[2 * q + 1]);
#pragma unroll
        for (int t = 0; t < 4; ++t) {
            if (idx[t] < NROWS) {
                load16(tmp, xf + (size_t)idx[t] * DDIM + k * 16);
                normalize16(tmp);
            } else {
#pragma unroll
                for (int d = 0; d < 16; ++d) tmp[d] = 0.f;
            }
#pragma unroll
            for (int q = 0; q < 8; ++q) z[t][q] = pack2(tmp[2 * q], tmp[2 * q + 1]);
        }
    }

    // xc/8, packed f16 (addend of every update FMA chain)
#pragma unroll
    for (int q = 0; q < 8; ++q) xch[q] = xch[q] * (_Float16)0.125f;

    // ---- iteration 0: p uniform = 1/8 ----
    float u[16];
#pragma unroll
    for (int q = 0; q < 8; ++q) {
#pragma unroll
        for (int g = 0; g < 2; ++g) {
            float acc = (float)xch[q][g];
            acc = mixfma(z[0][q][g], 0.125f, acc);
            acc = mixfma(z[1][q][g], 0.125f, acc);
            acc = mixfma(z[2][q][g], 0.125f, acc);
            acc = mixfma(z[3][q][g], 0.125f, acc);
            u[2 * q + g] = acc;
        }
    }
    butterfly8(u);
    float c = inv_norm_log2e(u);  // u kept raw; scale folded into dots
    h2 uh[8];
#pragma unroll
    for (int q = 0; q < 8; ++q) uh[q] = pack2(u[2 * q], u[2 * q + 1]);

    // ---- iterations 1..5 ----
#pragma unroll
    for (int it = 1; it < 6; ++it) {
        float pn[4];
#pragma unroll
        for (int t = 0; t < 4; ++t) {
            float a = hdot2(z[t][0], uh[0], 0.f);
            float b = hdot2(z[t][1], uh[1], 0.f);
#pragma unroll
            for (int q = 2; q < 8; q += 2) {
                a = hdot2(z[t][q], uh[q], a);
                b = hdot2(z[t][q + 1], uh[q + 1], b);
            }
            // p_hat = (z . u_raw) * rsqrt(ss); e = exp2(p_hat * log2e), |p_hat|<=1
            float e = fast_exp2((a + b) * c);
            float s = dpp_add<0x128>(e);  // xor 8: sum over capsules (stride-8 lanes)
            s += __shfl_xor(s, 16);
            s += __shfl_xor(s, 32);
            pn[t] = e * fast_rcp(s);
        }
#pragma unroll
        for (int q = 0; q < 8; ++q) {
#pragma unroll
            for (int g = 0; g < 2; ++g) {
                float acc = (float)xch[q][g];  // xc/8 folded into addend
                acc = mixfma(z[0][q][g], pn[0], acc);
                acc = mixfma(z[1][q][g], pn[1], acc);
                acc = mixfma(z[2][q][g], pn[2], acc);
                acc = mixfma(z[3][q][g], pn[3], acc);
                u[2 * q + g] = acc;
            }
        }
        butterfly8(u);
        if (it < 5) {  // last iteration NOT normalized
            c = inv_norm_log2e(u);
#pragma unroll
            for (int q = 0; q < 8; ++q) uh[q] = pack2(u[2 * q], u[2 * q + 1]);
        }
    }

    // ---- write: lane j stores dims (2j, 2j+1) of capsule k = out + n*128 + 2*lane.
    float w0 = u[0], w1 = u[1];
#pragma unroll
    for (int d = 1; d < 8; ++d) {
        if (j == d) { w0 = u[2 * d]; w1 = u[2 * d + 1]; }
    }
    *reinterpret_cast<float2*>(out + (size_t)n * DDIM + 2 * lane) = make_float2(w0, w1);
}

extern "C" void kernel_launch(void* const* d_in, const int* in_sizes, int n_in,
                              void* d_out, int out_size, void* d_ws, size_t ws_size,
                              hipStream_t stream) {
    const float* x = (const float*)d_in[0];
    const int* nbr = (const int*)d_in[1];
    float* out = (float*)d_out;

    const size_t need = (size_t)(NROWS + 1) * DDIM * sizeof(_Float16);
    if (ws_size >= need) {
        _Float16* xn = (_Float16*)d_ws;
        constexpr int TOTAL = (NROWS + 1) * (DDIM / 4);
        norm_kernel<<<(TOTAL + 255) / 256, 256, 0, stream>>>(x, xn);
        routing_kernel<true><<<NROWS / 4, 256, 0, stream>>>(xn, nbr, out);
    } else {
        routing_kernel<false><<<NROWS / 4, 256, 0, stream>>>(x, nbr, out);
    }
}

// Round 9
// 482.081 us; speedup vs baseline: 1.6155x; 1.6155x over previous
//
#include <hip/hip_runtime.h>
#include <math.h>

// RoutingLayer: N=50000 rows, M=32 neighbors, D=128 = K=8 capsules x 16 dims,
// 6 routing iterations. One wave per row; lane = k*8 + j owns ALL 16 dims of
// capsule k for the 4 neighbors m = j, j+8, j+16, j+24.
//
// r9 == r8 (round 8 hit a GPU-acquisition timeout; never ran).
// r8 == r7 with __launch_bounds__ back to (256,4). Theory: the (256,5) bound
// (introduced in r5 together with fp16 -- confounded) capped VGPRs at ~96 <
// ~110 live, so the allocator dumped z/xch/uh to scratch: VGPR_Count=48,
// 3.2GB HBM traffic, 721us. Cap 128 restores register residency.
//  - prologue normalizes x into an fp16 table xn[(N+1) x 128] (zero pad row N)
//  - z packed h2[4][8]; dots v_dot2_f32_f16; updates v_fma_mix
//  - butterfly / softmax / norm stay fp32

constexpr int NROWS = 50000;
constexpr int MN = 32;
constexpr int DDIM = 128;
constexpr float FEPS2 = 1e-24f;  // eps^2, eps = 1e-12 (torch F.normalize)
constexpr float LOG2E = 1.44269504088896340736f;

typedef _Float16 h2 __attribute__((ext_vector_type(2)));
typedef __fp16 fp16x2 __attribute__((ext_vector_type(2)));  // builtin ABI type

#if __has_builtin(__builtin_amdgcn_rcpf)
__device__ __forceinline__ float fast_rcp(float v) { return __builtin_amdgcn_rcpf(v); }
#else
__device__ __forceinline__ float fast_rcp(float v) { return __frcp_rn(v); }
#endif
#if __has_builtin(__builtin_amdgcn_rsqf)
__device__ __forceinline__ float fast_rsq(float v) { return __builtin_amdgcn_rsqf(v); }
#else
__device__ __forceinline__ float fast_rsq(float v) { return rsqrtf(v); }
#endif
#if __has_builtin(__builtin_amdgcn_exp2f)
__device__ __forceinline__ float fast_exp2(float v) { return __builtin_amdgcn_exp2f(v); }
#else
__device__ __forceinline__ float fast_exp2(float v) { return exp2f(v); }
#endif

// v + dpp_perm(v): quad_perm(1,0,3,2)=xor1 -> 0xB1; quad_perm(2,3,0,1)=xor2 -> 0x4E;
// row_ror:8 (xor8 within row of 16) -> 0x128. Fuses to a single v_add with DPP.
template <int CTRL>
__device__ __forceinline__ float dpp_add(float v) {
    int r = __builtin_amdgcn_update_dpp(0, __builtin_bit_cast(int, v), CTRL, 0xF, 0xF, true);
    return v + __builtin_bit_cast(float, r);
}

// fp32 accum dot of two f16 pairs: v_dot2_f32_f16.
__device__ __forceinline__ float hdot2(h2 a, h2 b, float c) {
#if __has_builtin(__builtin_amdgcn_fdot2)
    return __builtin_amdgcn_fdot2(__builtin_bit_cast(fp16x2, a),
                                  __builtin_bit_cast(fp16x2, b), c, false);
#else
    return fmaf((float)a[0], (float)b[0], fmaf((float)a[1], (float)b[1], c));
#endif
}

__device__ __forceinline__ h2 pack2(float a, float b) {
#if __has_builtin(__builtin_amdgcn_cvt_pkrtz)
    return __builtin_bit_cast(h2, __builtin_amdgcn_cvt_pkrtz(a, b));
#else
    h2 r; r[0] = (_Float16)a; r[1] = (_Float16)b; return r;
#endif
}

// fp16 src x fp32 scalar + fp32 acc -> v_fma_mix_f32 (pattern-matched by LLVM).
__device__ __forceinline__ float mixfma(_Float16 h, float s, float acc) {
    return fmaf((float)h, s, acc);
}

// Load 16 halves (32B) as two uint4 and scatter into 8 h2 regs (SROA-safe).
__device__ __forceinline__ void load8h2(h2 (&dst)[8], const _Float16* __restrict__ p) {
    const uint4* q = reinterpret_cast<const uint4*>(p);
    uint4 a = q[0], b = q[1];
    dst[0] = __builtin_bit_cast(h2, a.x);
    dst[1] = __builtin_bit_cast(h2, a.y);
    dst[2] = __builtin_bit_cast(h2, a.z);
    dst[3] = __builtin_bit_cast(h2, a.w);
    dst[4] = __builtin_bit_cast(h2, b.x);
    dst[5] = __builtin_bit_cast(h2, b.y);
    dst[6] = __builtin_bit_cast(h2, b.z);
    dst[7] = __builtin_bit_cast(h2, b.w);
}

__device__ __forceinline__ void load16(float (&dst)[16], const float* __restrict__ p) {
    const float4* q = reinterpret_cast<const float4*>(p);
#pragma unroll
    for (int i = 0; i < 4; ++i) {
        float4 v = q[i];
        dst[4 * i + 0] = v.x; dst[4 * i + 1] = v.y;
        dst[4 * i + 2] = v.z; dst[4 * i + 3] = v.w;
    }
}

__device__ __forceinline__ void normalize16(float (&v)[16]) {
    float a = v[0] * v[0], b = v[1] * v[1];
#pragma unroll
    for (int d = 2; d < 16; d += 2) {
        a = fmaf(v[d], v[d], a);
        b = fmaf(v[d + 1], v[d + 1], b);
    }
    float iv = fast_rsq(fmaxf(a + b, FEPS2));
#pragma unroll
    for (int d = 0; d < 16; ++d) v[d] *= iv;
}

// sum over the 8 j-lanes (lane bits 0..2), broadcast to all 8.
__device__ __forceinline__ void butterfly8(float (&u)[16]) {
#pragma unroll
    for (int d = 0; d < 16; ++d) u[d] = dpp_add<0xB1>(u[d]);
#pragma unroll
    for (int d = 0; d < 16; ++d) u[d] = dpp_add<0x4E>(u[d]);
#pragma unroll
    for (int d = 0; d < 16; ++d) u[d] += __shfl_xor(u[d], 4);
}

// rsqrt(max(||u||^2, eps^2)) * log2(e) -- combined dot-scale constant.
__device__ __forceinline__ float inv_norm_log2e(const float (&u)[16]) {
    float a = u[0] * u[0], b = u[1] * u[1];
#pragma unroll
    for (int d = 2; d < 16; d += 2) {
        a = fmaf(u[d], u[d], a);
        b = fmaf(u[d + 1], u[d + 1], b);
    }
    return fast_rsq(fmaxf(a + b, FEPS2)) * LOG2E;
}

// Prologue: per-capsule L2-normalize x into fp16 xn[(N+1) x 128]; row N = zeros.
// One float4 (input) per thread -> 4 halves (8B) out; lane-quad = one capsule.
__global__ __launch_bounds__(256) void norm_kernel(const float* __restrict__ x,
                                                   _Float16* __restrict__ xn) {
    int t = blockIdx.x * 256 + threadIdx.x;
    constexpr int TOTAL = (NROWS + 1) * (DDIM / 4);  // 50001*32
    if (t >= TOTAL) return;
    int n = t >> 5;
    float4 v = make_float4(0.f, 0.f, 0.f, 0.f);
    if (n < NROWS) v = reinterpret_cast<const float4*>(x)[t];
    float ss = v.x * v.x;
    ss = fmaf(v.y, v.y, ss);
    ss = fmaf(v.z, v.z, ss);
    ss = fmaf(v.w, v.w, ss);
    ss = dpp_add<0xB1>(ss);  // quad (4 threads) = one capsule (16 floats)
    ss = dpp_add<0x4E>(ss);
    float iv = fast_rsq(fmaxf(ss, FEPS2));
    h2 lo = pack2(v.x * iv, v.y * iv);
    h2 hi = pack2(v.z * iv, v.w * iv);
    float2 w;
    w.x = __builtin_bit_cast(float, lo);
    w.y = __builtin_bit_cast(float, hi);
    reinterpret_cast<float2*>(xn)[t] = w;  // 8B per thread
}

template <bool PRENORM>
__global__ __launch_bounds__(256, 4) void routing_kernel(const void* __restrict__ xsrc,
                                                         const int* __restrict__ nbr,
                                                         float* __restrict__ out) {
    const int lane = threadIdx.x & 63;
    const int n = blockIdx.x * 4 + (threadIdx.x >> 6);  // 12500*4 = 50000
    const int j = lane & 7;
    const int k = lane >> 3;

    const int* __restrict__ nrow = nbr + n * MN;
    int idx[4];
#pragma unroll
    for (int t = 0; t < 4; ++t) idx[t] = nrow[j + 8 * t];

    h2 z[4][8];   // 4 neighbors x 16 dims, packed f16 pairs (32 VGPRs)
    h2 xch[8];    // own capsule, packed f16 (later scaled by 1/8)

    if constexpr (PRENORM) {
        const _Float16* xh = (const _Float16*)xsrc;
        load8h2(xch, xh + (size_t)n * DDIM + k * 16);
#pragma unroll
        for (int t = 0; t < 4; ++t) {
            // idx == NROWS hits the zero pad row: no bounds check, no normalize
            load8h2(z[t], xh + (size_t)idx[t] * DDIM + k * 16);
        }
    } else {
        const float* xf = (const float*)xsrc;
        float tmp[16];
        load16(tmp, xf + (size_t)n * DDIM + k * 16);
        normalize16(tmp);
#pragma unroll
        for (int q = 0; q < 8; ++q) xch[q] = pack2(tmp[2 * q], tmp[2 * q + 1]);
#pragma unroll
        for (int t = 0; t < 4; ++t) {
            if (idx[t] < NROWS) {
                load16(tmp, xf + (size_t)idx[t] * DDIM + k * 16);
                normalize16(tmp);
            } else {
#pragma unroll
                for (int d = 0; d < 16; ++d) tmp[d] = 0.f;
            }
#pragma unroll
            for (int q = 0; q < 8; ++q) z[t][q] = pack2(tmp[2 * q], tmp[2 * q + 1]);
        }
    }

    // xc/8, packed f16 (addend of every update FMA chain)
#pragma unroll
    for (int q = 0; q < 8; ++q) xch[q] = xch[q] * (_Float16)0.125f;

    // ---- iteration 0: p uniform = 1/8 ----
    float u[16];
#pragma unroll
    for (int q = 0; q < 8; ++q) {
#pragma unroll
        for (int g = 0; g < 2; ++g) {
            float acc = (float)xch[q][g];
            acc = mixfma(z[0][q][g], 0.125f, acc);
            acc = mixfma(z[1][q][g], 0.125f, acc);
            acc = mixfma(z[2][q][g], 0.125f, acc);
            acc = mixfma(z[3][q][g], 0.125f, acc);
            u[2 * q + g] = acc;
        }
    }
    butterfly8(u);
    float c = inv_norm_log2e(u);  // u kept raw; scale folded into dots
    h2 uh[8];
#pragma unroll
    for (int q = 0; q < 8; ++q) uh[q] = pack2(u[2 * q], u[2 * q + 1]);

    // ---- iterations 1..5 ----
#pragma unroll
    for (int it = 1; it < 6; ++it) {
        float pn[4];
#pragma unroll
        for (int t = 0; t < 4; ++t) {
            float a = hdot2(z[t][0], uh[0], 0.f);
            float b = hdot2(z[t][1], uh[1], 0.f);
#pragma unroll
            for (int q = 2; q < 8; q += 2) {
                a = hdot2(z[t][q], uh[q], a);
                b = hdot2(z[t][q + 1], uh[q + 1], b);
            }
            // p_hat = (z . u_raw) * rsqrt(ss); e = exp2(p_hat * log2e), |p_hat|<=1
            float e = fast_exp2((a + b) * c);
            float s = dpp_add<0x128>(e);  // xor 8: sum over capsules (stride-8 lanes)
            s += __shfl_xor(s, 16);
            s += __shfl_xor(s, 32);
            pn[t] = e * fast_rcp(s);
        }
#pragma unroll
        for (int q = 0; q < 8; ++q) {
#pragma unroll
            for (int g = 0; g < 2; ++g) {
                float acc = (float)xch[q][g];  // xc/8 folded into addend
                acc = mixfma(z[0][q][g], pn[0], acc);
                acc = mixfma(z[1][q][g], pn[1], acc);
                acc = mixfma(z[2][q][g], pn[2], acc);
                acc = mixfma(z[3][q][g], pn[3], acc);
                u[2 * q + g] = acc;
            }
        }
        butterfly8(u);
        if (it < 5) {  // last iteration NOT normalized
            c = inv_norm_log2e(u);
#pragma unroll
            for (int q = 0; q < 8; ++q) uh[q] = pack2(u[2 * q], u[2 * q + 1]);
        }
    }

    // ---- write: lane j stores dims (2j, 2j+1) of capsule k = out + n*128 + 2*lane.
    float w0 = u[0], w1 = u[1];
#pragma unroll
    for (int d = 1; d < 8; ++d) {
        if (j == d) { w0 = u[2 * d]; w1 = u[2 * d + 1]; }
    }
    *reinterpret_cast<float2*>(out + (size_t)n * DDIM + 2 * lane) = make_float2(w0, w1);
}

extern "C" void kernel_launch(void* const* d_in, const int* in_sizes, int n_in,
                              void* d_out, int out_size, void* d_ws, size_t ws_size,
                              hipStream_t stream) {
    const float* x = (const float*)d_in[0];
    const int* nbr = (const int*)d_in[1];
    float* out = (float*)d_out;

    const size_t need = (size_t)(NROWS + 1) * DDIM * sizeof(_Float16);
    if (ws_size >= need) {
        _Float16* xn = (_Float16*)d_ws;
        constexpr int TOTAL = (NROWS + 1) * (DDIM / 4);
        norm_kernel<<<(TOTAL + 255) / 256, 256, 0, stream>>>(x, xn);
        routing_kernel<true><<<NROWS / 4, 256, 0, stream>>>(xn, nbr, out);
    } else {
        routing_kernel<false><<<NROWS / 4, 256, 0, stream>>>(x, nbr, out);
    }
}